// Round 1
// baseline (7890.616 us; speedup 1.0000x reference)
//
#include <hip/hip_runtime.h>
#include <hip/hip_bf16.h>

// Model dims
#define WLEN 2048
#define EDIM 256
#define DDIM 512
#define NLAYER 4
#define NCLS 5
#define DI 1024
#define DS 64
#define DR 32
#define DC 4
#define BB 2
#define TOK (BB*WLEN)   // 4096 tokens

// ---------------------------------------------------------------------------
// Embed: x[bl][e] = byte_embed[seq[bl]][e] + pos_embed[l][e]
__global__ __launch_bounds__(256) void embed_k(const int* __restrict__ seq,
    const float* __restrict__ be, const float* __restrict__ pe,
    float* __restrict__ out)
{
    int idx = blockIdx.x * 256 + threadIdx.x;      // [0, TOK*EDIM)
    int e  = idx & (EDIM - 1);
    int bl = idx >> 8;
    int l  = bl & (WLEN - 1);
    int tok = seq[bl];
    out[idx] = be[tok * EDIM + e] + pe[l * EDIM + e];
}

// ---------------------------------------------------------------------------
// LayerNorm over 512 cols, one wave per row (8 elems/lane)
__global__ __launch_bounds__(256) void ln_k(const float* __restrict__ x,
    const float* __restrict__ g, const float* __restrict__ b,
    float* __restrict__ out)
{
    int row  = blockIdx.x * 4 + (threadIdx.x >> 6);
    int lane = threadIdx.x & 63;
    const float* xp = x + (size_t)row * DDIM;
    float v[8];
    float s = 0.f;
#pragma unroll
    for (int i = 0; i < 8; i++) { v[i] = xp[lane + 64 * i]; s += v[i]; }
#pragma unroll
    for (int off = 32; off; off >>= 1) s += __shfl_xor(s, off, 64);
    float mu = s * (1.f / 512.f);
    float s2 = 0.f;
#pragma unroll
    for (int i = 0; i < 8; i++) { float d = v[i] - mu; s2 += d * d; }
#pragma unroll
    for (int off = 32; off; off >>= 1) s2 += __shfl_xor(s2, off, 64);
    float rs = rsqrtf(s2 * (1.f / 512.f) + 1e-5f);
#pragma unroll
    for (int i = 0; i < 8; i++) {
        int c = lane + 64 * i;
        out[(size_t)row * DDIM + c] = (v[i] - mu) * rs * g[c] + b[c];
    }
}

// ---------------------------------------------------------------------------
// Depthwise causal conv (width 4) + bias + silu.
// xr layout: [TOK][2*DI], xs part is cols [0,DI). Output xs: [TOK][DI].
__global__ __launch_bounds__(256) void conv_silu_k(const float* __restrict__ xr,
    const float* __restrict__ cw, const float* __restrict__ cb,
    float* __restrict__ xs)
{
    int idx = blockIdx.x * 256 + threadIdx.x;      // [0, TOK*DI)
    int d  = idx & (DI - 1);
    int bl = idx >> 10;
    int l  = bl & (WLEN - 1);
    float acc = cb[d];
    const float* wp = cw + d * DC;
#pragma unroll
    for (int k = 0; k < DC; k++) {
        int ls = l - (DC - 1) + k;
        if (ls >= 0)
            acc = fmaf(xr[((size_t)(bl - (DC - 1) + k)) * (2 * DI) + d], wp[k], acc);
    }
    xs[idx] = acc / (1.f + __expf(-acc));          // silu
}

// ---------------------------------------------------------------------------
// Selective scan. One wave per (b,d) channel; lane = state index s.
// delta buffer is read and overwritten in-place with the gated output y.
__global__ __launch_bounds__(256) void scan_k(
    float* __restrict__ delta,          // [TOK][DI]  in: delta, out: y
    const float* __restrict__ xdbl,     // [TOK][DR+2*DS]
    const float* __restrict__ xs,       // [TOK][DI]
    const float* __restrict__ xr,       // [TOK][2*DI], res part at +DI
    const float* __restrict__ A_log,    // [DI][DS]
    const float* __restrict__ Dp)       // [DI]
{
    int wid  = blockIdx.x * 4 + (threadIdx.x >> 6);  // 0..2047
    int lane = threadIdx.x & 63;
    int b = wid >> 10;
    int d = wid & (DI - 1);
    float Aa  = -__expf(A_log[d * DS + lane]);
    float Dpd = Dp[d];
    float hst = 0.f;
    size_t base = (size_t)b * WLEN;
    for (int t = 0; t < WLEN; t++) {
        size_t bl = base + t;
        float dlt = delta[bl * DI + d];
        float xv  = xs[bl * DI + d];
        float Bt  = xdbl[bl * (DR + 2 * DS) + DR + lane];
        float Ct  = xdbl[bl * (DR + 2 * DS) + DR + DS + lane];
        float dA = __expf(dlt * Aa);
        hst = fmaf(dA, hst, dlt * xv * Bt);
        float p = hst * Ct;
#pragma unroll
        for (int off = 32; off; off >>= 1) p += __shfl_xor(p, off, 64);
        float r  = xr[bl * (2 * DI) + DI + d];
        float yv = (p + xv * Dpd) * (r / (1.f + __expf(-r)));
        if (lane == 0) delta[bl * DI + d] = yv;
    }
}

// ---------------------------------------------------------------------------
// Generic f32 NT GEMM: C[M][N] = A[M][K] * W[N][K]^T (+ epilogue)
// EPI: 0 = none, 1 = +bias, 2 = relu(+bias), 3 = softplus(+bias), 4 = +resid
template<int EPI>
__global__ __launch_bounds__(256) void gemm_nt(
    const float* __restrict__ A, int lda,
    const float* __restrict__ W, int ldw,
    const float* __restrict__ bias,
    const float* __restrict__ resid, int ldr,
    float* __restrict__ C, int ldc,
    int M, int N, int K)
{
    __shared__ float As[16][64];
    __shared__ float Ws[16][64];
    const int tid = threadIdx.x;
    const int tx = tid & 15;
    const int ty = tid >> 4;
    const int bm = blockIdx.x * 64;
    const int bn = blockIdx.y * 64;
    const int lr = tid >> 2;           // 0..63: row within tile
    const int lc = (tid & 3) << 2;     // 0,4,8,12: k offset
    float acc[4][4] = {};
    for (int k0 = 0; k0 < K; k0 += 16) {
        float4 av = *(const float4*)(A + (size_t)(bm + lr) * lda + (k0 + lc));
        float4 wv = make_float4(0.f, 0.f, 0.f, 0.f);
        if (bn + lr < N)
            wv = *(const float4*)(W + (size_t)(bn + lr) * ldw + (k0 + lc));
        As[lc + 0][lr] = av.x; As[lc + 1][lr] = av.y;
        As[lc + 2][lr] = av.z; As[lc + 3][lr] = av.w;
        Ws[lc + 0][lr] = wv.x; Ws[lc + 1][lr] = wv.y;
        Ws[lc + 2][lr] = wv.z; Ws[lc + 3][lr] = wv.w;
        __syncthreads();
#pragma unroll
        for (int k = 0; k < 16; ++k) {
            float4 a = *(const float4*)&As[k][ty * 4];
            float4 w = *(const float4*)&Ws[k][tx * 4];
            float aa[4] = {a.x, a.y, a.z, a.w};
            float ww[4] = {w.x, w.y, w.z, w.w};
#pragma unroll
            for (int i = 0; i < 4; i++)
#pragma unroll
                for (int j = 0; j < 4; j++)
                    acc[i][j] = fmaf(aa[i], ww[j], acc[i][j]);
        }
        __syncthreads();
    }
#pragma unroll
    for (int i = 0; i < 4; i++) {
        int m = bm + ty * 4 + i;
#pragma unroll
        for (int j = 0; j < 4; j++) {
            int n = bn + tx * 4 + j;
            if (n >= N) continue;
            float v = acc[i][j];
            if (EPI == 1 || EPI == 2 || EPI == 3) v += bias[n];
            if (EPI == 2) v = fmaxf(v, 0.f);
            if (EPI == 3) v = fmaxf(v, 0.f) + log1pf(__expf(-fabsf(v)));
            if (EPI == 4) v += resid[(size_t)m * ldr + n];
            C[(size_t)m * ldc + n] = v;
        }
    }
}

// ---------------------------------------------------------------------------
extern "C" void kernel_launch(void* const* d_in, const int* in_sizes, int n_in,
                              void* d_out, int out_size, void* d_ws, size_t ws_size,
                              hipStream_t stream)
{
    const int*   seq        = (const int*)d_in[0];
    const float* byte_embed = (const float*)d_in[1];
    const float* pos_embed  = (const float*)d_in[2];
    const float* in_w       = (const float*)d_in[3];
    const float* in_b       = (const float*)d_in[4];
    const float* ln_g       = (const float*)d_in[5];
    const float* ln_b       = (const float*)d_in[6];
    const float* m_in_w     = (const float*)d_in[7];
    const float* conv_w     = (const float*)d_in[8];
    const float* conv_b     = (const float*)d_in[9];
    const float* xp_w       = (const float*)d_in[10];
    const float* dt_w       = (const float*)d_in[11];
    const float* dt_b       = (const float*)d_in[12];
    const float* A_log      = (const float*)d_in[13];
    const float* Dp         = (const float*)d_in[14];
    const float* m_out_w    = (const float*)d_in[15];
    const float* h1_w       = (const float*)d_in[16];
    const float* h1_b       = (const float*)d_in[17];
    const float* h2_w       = (const float*)d_in[18];
    const float* h2_b       = (const float*)d_in[19];
    const float* h3_w       = (const float*)d_in[20];
    const float* h3_b       = (const float*)d_in[21];
    float* out = (float*)d_out;

    float* ws = (float*)d_ws;
    size_t off = 0;
    float* xe    = ws + off; off += (size_t)TOK * EDIM;      // 4096x256
    float* x     = ws + off; off += (size_t)TOK * DDIM;      // 4096x512 (residual stream)
    float* h     = ws + off; off += (size_t)TOK * DDIM;      // 4096x512 (ln out; reused as t2)
    float* xr    = ws + off; off += (size_t)TOK * 2 * DI;    // 4096x2048
    float* xs    = ws + off; off += (size_t)TOK * DI;        // 4096x1024
    float* xdbl  = ws + off; off += (size_t)TOK * (DR+2*DS); // 4096x160
    float* delta = ws + off; off += (size_t)TOK * DI;        // 4096x1024 (also y, in place)
    float* t1 = xe;   // head temp 4096x256 (embed no longer needed)
    float* t2 = h;    // head temp 4096x128

    // Embed + input projection
    embed_k<<<TOK * EDIM / 256, 256, 0, stream>>>(seq, byte_embed, pos_embed, xe);
    gemm_nt<1><<<dim3(TOK/64, DDIM/64), 256, 0, stream>>>(
        xe, EDIM, in_w, EDIM, in_b, nullptr, 0, x, DDIM, TOK, DDIM, EDIM);

    for (int i = 0; i < NLAYER; i++) {
        const float* lg  = ln_g  + (size_t)i * DDIM;
        const float* lb  = ln_b  + (size_t)i * DDIM;
        const float* miw = m_in_w + (size_t)i * 2 * DI * DDIM;
        const float* cw  = conv_w + (size_t)i * DI * DC;
        const float* cb  = conv_b + (size_t)i * DI;
        const float* xpw = xp_w  + (size_t)i * (DR + 2 * DS) * DI;
        const float* dtw = dt_w  + (size_t)i * DI * DR;
        const float* dtb = dt_b  + (size_t)i * DI;
        const float* al  = A_log + (size_t)i * DI * DS;
        const float* dp  = Dp    + (size_t)i * DI;
        const float* mow = m_out_w + (size_t)i * DDIM * DI;

        ln_k<<<TOK/4, 256, 0, stream>>>(x, lg, lb, h);
        gemm_nt<0><<<dim3(TOK/64, 2*DI/64), 256, 0, stream>>>(
            h, DDIM, miw, DDIM, nullptr, nullptr, 0, xr, 2*DI, TOK, 2*DI, DDIM);
        conv_silu_k<<<TOK * DI / 256, 256, 0, stream>>>(xr, cw, cb, xs);
        gemm_nt<0><<<dim3(TOK/64, (DR+2*DS+63)/64), 256, 0, stream>>>(
            xs, DI, xpw, DI, nullptr, nullptr, 0, xdbl, DR+2*DS, TOK, DR+2*DS, DI);
        gemm_nt<3><<<dim3(TOK/64, DI/64), 256, 0, stream>>>(
            xdbl, DR+2*DS, dtw, DR, dtb, nullptr, 0, delta, DI, TOK, DI, DR);
        scan_k<<<BB * DI / 4, 256, 0, stream>>>(delta, xdbl, xs, xr, al, dp);
        gemm_nt<4><<<dim3(TOK/64, DDIM/64), 256, 0, stream>>>(
            delta, DI, mow, DI, nullptr, x, DDIM, x, DDIM, TOK, DDIM, DI);
    }

    // Head
    gemm_nt<2><<<dim3(TOK/64, 256/64), 256, 0, stream>>>(
        x, DDIM, h1_w, DDIM, h1_b, nullptr, 0, t1, 256, TOK, 256, DDIM);
    gemm_nt<2><<<dim3(TOK/64, 2), 256, 0, stream>>>(
        t1, 256, h2_w, 256, h2_b, nullptr, 0, t2, 128, TOK, 128, 256);
    gemm_nt<1><<<dim3(TOK/64, 1), 256, 0, stream>>>(
        t2, 128, h3_w, 128, h3_b, nullptr, 0, out, NCLS, TOK, NCLS, 128);
}

// Round 2
// 3150.021 us; speedup vs baseline: 2.5049x; 2.5049x over previous
//
#include <hip/hip_runtime.h>
#include <hip/hip_bf16.h>

// Model dims
#define WLEN 2048
#define EDIM 256
#define DDIM 512
#define NLAYER 4
#define NCLS 5
#define DI 1024
#define DS 64
#define DR 32
#define DC 4
#define BB 2
#define TOK (BB*WLEN)   // 4096 tokens
#define XD (DR + 2*DS)  // 160

// ---------------------------------------------------------------------------
// Embed: x[bl][e] = byte_embed[seq[bl]][e] + pos_embed[l][e]
__global__ __launch_bounds__(256) void embed_k(const int* __restrict__ seq,
    const float* __restrict__ be, const float* __restrict__ pe,
    float* __restrict__ out)
{
    int idx = blockIdx.x * 256 + threadIdx.x;      // [0, TOK*EDIM)
    int e  = idx & (EDIM - 1);
    int bl = idx >> 8;
    int l  = bl & (WLEN - 1);
    int tok = seq[bl];
    out[idx] = be[tok * EDIM + e] + pe[l * EDIM + e];
}

// ---------------------------------------------------------------------------
// LayerNorm over 512 cols, one wave per row (8 elems/lane)
__global__ __launch_bounds__(256) void ln_k(const float* __restrict__ x,
    const float* __restrict__ g, const float* __restrict__ b,
    float* __restrict__ out)
{
    int row  = blockIdx.x * 4 + (threadIdx.x >> 6);
    int lane = threadIdx.x & 63;
    const float* xp = x + (size_t)row * DDIM;
    float v[8];
    float s = 0.f;
#pragma unroll
    for (int i = 0; i < 8; i++) { v[i] = xp[lane + 64 * i]; s += v[i]; }
#pragma unroll
    for (int off = 32; off; off >>= 1) s += __shfl_xor(s, off, 64);
    float mu = s * (1.f / 512.f);
    float s2 = 0.f;
#pragma unroll
    for (int i = 0; i < 8; i++) { float d = v[i] - mu; s2 += d * d; }
#pragma unroll
    for (int off = 32; off; off >>= 1) s2 += __shfl_xor(s2, off, 64);
    float rs = rsqrtf(s2 * (1.f / 512.f) + 1e-5f);
#pragma unroll
    for (int i = 0; i < 8; i++) {
        int c = lane + 64 * i;
        out[(size_t)row * DDIM + c] = (v[i] - mu) * rs * g[c] + b[c];
    }
}

// ---------------------------------------------------------------------------
// Depthwise causal conv (width 4) + bias + silu.
__global__ __launch_bounds__(256) void conv_silu_k(const float* __restrict__ xr,
    const float* __restrict__ cw, const float* __restrict__ cb,
    float* __restrict__ xs)
{
    int idx = blockIdx.x * 256 + threadIdx.x;      // [0, TOK*DI)
    int d  = idx & (DI - 1);
    int bl = idx >> 10;
    int l  = bl & (WLEN - 1);
    float acc = cb[d];
    const float* wp = cw + d * DC;
#pragma unroll
    for (int k = 0; k < DC; k++) {
        int ls = l - (DC - 1) + k;
        if (ls >= 0)
            acc = fmaf(xr[((size_t)(bl - (DC - 1) + k)) * (2 * DI) + d], wp[k], acc);
    }
    xs[idx] = acc / (1.f + __expf(-acc));          // silu
}

// ---------------------------------------------------------------------------
// Selective scan, 8-step software-pipelined, double-buffered load groups.
// One wave per (b,d) channel; lane = state index s.
// delta buffer is read and overwritten in-place with the gated output y.
#define SU 8

#define LOADG(T0, dlt, xv, Bt, Ct, rr)                                   \
  _Pragma("unroll")                                                      \
  for (int u = 0; u < SU; u++) {                                         \
    size_t bl = base + (size_t)(T0) + u;                                 \
    dlt[u] = delta[bl * DI + d];                                         \
    xv[u]  = xs[bl * DI + d];                                            \
    Bt[u]  = xdbl[bl * XD + DR + lane];                                  \
    Ct[u]  = xdbl[bl * XD + DR + DS + lane];                             \
    rr[u]  = xr[bl * (2 * DI) + DI + d];                                 \
  }

#define COMPG(T0, dlt, xv, Bt, Ct, rr)                                   \
  {                                                                      \
    float dA[SU], p[SU];                                                 \
    _Pragma("unroll")                                                    \
    for (int u = 0; u < SU; u++) dA[u] = __expf(dlt[u] * Aa);            \
    _Pragma("unroll")                                                    \
    for (int u = 0; u < SU; u++) {                                       \
      hst = fmaf(dA[u], hst, dlt[u] * xv[u] * Bt[u]);                    \
      p[u] = hst * Ct[u];                                                \
    }                                                                    \
    _Pragma("unroll")                                                    \
    for (int off = 32; off; off >>= 1) {                                 \
      _Pragma("unroll")                                                  \
      for (int u = 0; u < SU; u++) p[u] += __shfl_xor(p[u], off, 64);    \
    }                                                                    \
    _Pragma("unroll")                                                    \
    for (int u = 0; u < SU; u++) {                                       \
      float yv = (p[u] + xv[u] * Dpd) *                                  \
                 (rr[u] / (1.f + __expf(-rr[u])));                       \
      if (lane == u) delta[(base + (size_t)(T0) + u) * DI + d] = yv;     \
    }                                                                    \
  }

__global__ __launch_bounds__(256) void scan_k(
    float* __restrict__ delta,          // [TOK][DI]  in: delta, out: y
    const float* __restrict__ xdbl,     // [TOK][XD]
    const float* __restrict__ xs,       // [TOK][DI]
    const float* __restrict__ xr,       // [TOK][2*DI], res part at +DI
    const float* __restrict__ A_log,    // [DI][DS]
    const float* __restrict__ Dp)       // [DI]
{
    int wid  = blockIdx.x * 4 + (threadIdx.x >> 6);  // 0..2047
    int lane = threadIdx.x & 63;
    int b = wid >> 10;
    int d = wid & (DI - 1);
    float Aa  = -__expf(A_log[d * DS + lane]);
    float Dpd = Dp[d];
    float hst = 0.f;
    size_t base = (size_t)b * WLEN;

    float da[SU], xa[SU], Ba[SU], Ca[SU], ra[SU];
    float db[SU], xb[SU], Bb[SU], Cb[SU], rb[SU];

    LOADG(0, da, xa, Ba, Ca, ra)
    for (int t0 = 0; t0 < WLEN; t0 += 2 * SU) {
        LOADG(t0 + SU, db, xb, Bb, Cb, rb)       // prefetch group B
        COMPG(t0, da, xa, Ba, Ca, ra)            // compute+store group A
        if (t0 + 2 * SU < WLEN)
            LOADG(t0 + 2 * SU, da, xa, Ba, Ca, ra)  // prefetch next group A
        COMPG(t0 + SU, db, xb, Bb, Cb, rb)       // compute+store group B
    }
}

// ---------------------------------------------------------------------------
// Generic f32 NT GEMM: C[M][N] = A[M][K] * W[N][K]^T (+ epilogue)
// EPI: 0 = none, 1 = +bias, 2 = relu(+bias), 3 = softplus(+bias), 4 = +resid
template<int EPI>
__global__ __launch_bounds__(256) void gemm_nt(
    const float* __restrict__ A, int lda,
    const float* __restrict__ W, int ldw,
    const float* __restrict__ bias,
    const float* __restrict__ resid, int ldr,
    float* __restrict__ C, int ldc,
    int M, int N, int K)
{
    __shared__ float As[16][64];
    __shared__ float Ws[16][64];
    const int tid = threadIdx.x;
    const int tx = tid & 15;
    const int ty = tid >> 4;
    const int bm = blockIdx.x * 64;
    const int bn = blockIdx.y * 64;
    const int lr = tid >> 2;           // 0..63: row within tile
    const int lc = (tid & 3) << 2;     // 0,4,8,12: k offset
    float acc[4][4] = {};
    for (int k0 = 0; k0 < K; k0 += 16) {
        float4 av = *(const float4*)(A + (size_t)(bm + lr) * lda + (k0 + lc));
        float4 wv = make_float4(0.f, 0.f, 0.f, 0.f);
        if (bn + lr < N)
            wv = *(const float4*)(W + (size_t)(bn + lr) * ldw + (k0 + lc));
        As[lc + 0][lr] = av.x; As[lc + 1][lr] = av.y;
        As[lc + 2][lr] = av.z; As[lc + 3][lr] = av.w;
        Ws[lc + 0][lr] = wv.x; Ws[lc + 1][lr] = wv.y;
        Ws[lc + 2][lr] = wv.z; Ws[lc + 3][lr] = wv.w;
        __syncthreads();
#pragma unroll
        for (int k = 0; k < 16; ++k) {
            float4 a = *(const float4*)&As[k][ty * 4];
            float4 w = *(const float4*)&Ws[k][tx * 4];
            float aa[4] = {a.x, a.y, a.z, a.w};
            float ww[4] = {w.x, w.y, w.z, w.w};
#pragma unroll
            for (int i = 0; i < 4; i++)
#pragma unroll
                for (int j = 0; j < 4; j++)
                    acc[i][j] = fmaf(aa[i], ww[j], acc[i][j]);
        }
        __syncthreads();
    }
#pragma unroll
    for (int i = 0; i < 4; i++) {
        int m = bm + ty * 4 + i;
#pragma unroll
        for (int j = 0; j < 4; j++) {
            int n = bn + tx * 4 + j;
            if (n >= N) continue;
            float v = acc[i][j];
            if (EPI == 1 || EPI == 2 || EPI == 3) v += bias[n];
            if (EPI == 2) v = fmaxf(v, 0.f);
            if (EPI == 3) v = fmaxf(v, 0.f) + log1pf(__expf(-fabsf(v)));
            if (EPI == 4) v += resid[(size_t)m * ldr + n];
            C[(size_t)m * ldc + n] = v;
        }
    }
}

// ---------------------------------------------------------------------------
extern "C" void kernel_launch(void* const* d_in, const int* in_sizes, int n_in,
                              void* d_out, int out_size, void* d_ws, size_t ws_size,
                              hipStream_t stream)
{
    const int*   seq        = (const int*)d_in[0];
    const float* byte_embed = (const float*)d_in[1];
    const float* pos_embed  = (const float*)d_in[2];
    const float* in_w       = (const float*)d_in[3];
    const float* in_b       = (const float*)d_in[4];
    const float* ln_g       = (const float*)d_in[5];
    const float* ln_b       = (const float*)d_in[6];
    const float* m_in_w     = (const float*)d_in[7];
    const float* conv_w     = (const float*)d_in[8];
    const float* conv_b     = (const float*)d_in[9];
    const float* xp_w       = (const float*)d_in[10];
    const float* dt_w       = (const float*)d_in[11];
    const float* dt_b       = (const float*)d_in[12];
    const float* A_log      = (const float*)d_in[13];
    const float* Dp         = (const float*)d_in[14];
    const float* m_out_w    = (const float*)d_in[15];
    const float* h1_w       = (const float*)d_in[16];
    const float* h1_b       = (const float*)d_in[17];
    const float* h2_w       = (const float*)d_in[18];
    const float* h2_b       = (const float*)d_in[19];
    const float* h3_w       = (const float*)d_in[20];
    const float* h3_b       = (const float*)d_in[21];
    float* out = (float*)d_out;

    float* ws = (float*)d_ws;
    size_t off = 0;
    float* xe    = ws + off; off += (size_t)TOK * EDIM;      // 4096x256
    float* x     = ws + off; off += (size_t)TOK * DDIM;      // 4096x512 (residual stream)
    float* h     = ws + off; off += (size_t)TOK * DDIM;      // 4096x512 (ln out; reused as t2)
    float* xr    = ws + off; off += (size_t)TOK * 2 * DI;    // 4096x2048
    float* xs    = ws + off; off += (size_t)TOK * DI;        // 4096x1024
    float* xdbl  = ws + off; off += (size_t)TOK * XD;        // 4096x160
    float* delta = ws + off; off += (size_t)TOK * DI;        // 4096x1024 (also y, in place)
    float* t1 = xe;   // head temp 4096x256 (embed no longer needed)
    float* t2 = h;    // head temp 4096x128

    // Embed + input projection
    embed_k<<<TOK * EDIM / 256, 256, 0, stream>>>(seq, byte_embed, pos_embed, xe);
    gemm_nt<1><<<dim3(TOK/64, DDIM/64), 256, 0, stream>>>(
        xe, EDIM, in_w, EDIM, in_b, nullptr, 0, x, DDIM, TOK, DDIM, EDIM);

    for (int i = 0; i < NLAYER; i++) {
        const float* lg  = ln_g  + (size_t)i * DDIM;
        const float* lb  = ln_b  + (size_t)i * DDIM;
        const float* miw = m_in_w + (size_t)i * 2 * DI * DDIM;
        const float* cw  = conv_w + (size_t)i * DI * DC;
        const float* cb  = conv_b + (size_t)i * DI;
        const float* xpw = xp_w  + (size_t)i * XD * DI;
        const float* dtw = dt_w  + (size_t)i * DI * DR;
        const float* dtb = dt_b  + (size_t)i * DI;
        const float* al  = A_log + (size_t)i * DI * DS;
        const float* dp  = Dp    + (size_t)i * DI;
        const float* mow = m_out_w + (size_t)i * DDIM * DI;

        ln_k<<<TOK/4, 256, 0, stream>>>(x, lg, lb, h);
        gemm_nt<0><<<dim3(TOK/64, 2*DI/64), 256, 0, stream>>>(
            h, DDIM, miw, DDIM, nullptr, nullptr, 0, xr, 2*DI, TOK, 2*DI, DDIM);
        conv_silu_k<<<TOK * DI / 256, 256, 0, stream>>>(xr, cw, cb, xs);
        gemm_nt<0><<<dim3(TOK/64, (XD+63)/64), 256, 0, stream>>>(
            xs, DI, xpw, DI, nullptr, nullptr, 0, xdbl, XD, TOK, XD, DI);
        gemm_nt<3><<<dim3(TOK/64, DI/64), 256, 0, stream>>>(
            xdbl, XD, dtw, DR, dtb, nullptr, 0, delta, DI, TOK, DI, DR);
        scan_k<<<BB * DI / 4, 256, 0, stream>>>(delta, xdbl, xs, xr, al, dp);
        gemm_nt<4><<<dim3(TOK/64, DDIM/64), 256, 0, stream>>>(
            delta, DI, mow, DI, nullptr, x, DDIM, x, DDIM, TOK, DDIM, DI);
    }

    // Head
    gemm_nt<2><<<dim3(TOK/64, 256/64), 256, 0, stream>>>(
        x, DDIM, h1_w, DDIM, h1_b, nullptr, 0, t1, 256, TOK, 256, DDIM);
    gemm_nt<2><<<dim3(TOK/64, 2), 256, 0, stream>>>(
        t1, 256, h2_w, 256, h2_b, nullptr, 0, t2, 128, TOK, 128, 256);
    gemm_nt<1><<<dim3(TOK/64, 1), 256, 0, stream>>>(
        t2, 128, h3_w, 128, h3_b, nullptr, 0, out, NCLS, TOK, NCLS, 128);
}